// Round 15
// baseline (155.066 us; speedup 1.0000x reference)
//
#include <hip/hip_runtime.h>

// ---------------------------------------------------------------------------
// QuantumQKGenerator, fully fused (R17): out[b] = expectations of
// S = QFT * U_circuit * normalize(x[b]).  One wave per row, amps in regs.
//
// R16 post-mortem: 97 -> 89.5us, VALUBusy 81%, conflicts 2.25M -> 285K.
// Kernel is VALU-issue-bound (~72us issue + ~17us stall).  R17 diet:
//  1) xor32 -> permlane32_swap (1 VALU + cndmask, no DS pipe) for the
//     ~126 remaining __shfl_xor (wred tails + e=5 stages)
//  2) rr/ii packed into ONE butterfly by lane parity (even lanes sum rr,
//     odd sum ii; pack stage + 5 shared stages + parity-fix lxor) for all
//     10 qubits: 24 -> 17 ops each
//  3) cross-qubit zz = Walsh coefficients W[2^e] of P2s: one 6-stage WHT
//     (18 ops) + 6 readlane replaces 6 wreds (72 ops)
//  4) gate stage p=0 peeled: input amps real (y=0), half the math
// ---------------------------------------------------------------------------

// cross-lane XOR exchange; e is compile-time after full unroll.
__device__ __forceinline__ float lxor(float v, int e) {
    if (e == 0)        // quad_perm [1,0,3,2]
        return __builtin_bit_cast(float, __builtin_amdgcn_mov_dpp(
            __builtin_bit_cast(int, v), 0xB1, 0xF, 0xF, true));
    else if (e == 1)   // quad_perm [2,3,0,1]
        return __builtin_bit_cast(float, __builtin_amdgcn_mov_dpp(
            __builtin_bit_cast(int, v), 0x4E, 0xF, 0xF, true));
    else if (e == 2)   // ds_swizzle bit-mode xor4
        return __builtin_bit_cast(float, __builtin_amdgcn_ds_swizzle(
            __builtin_bit_cast(int, v), (4 << 10) | 0x1F));
    else if (e == 3)   // xor8
        return __builtin_bit_cast(float, __builtin_amdgcn_ds_swizzle(
            __builtin_bit_cast(int, v), (8 << 10) | 0x1F));
    else if (e == 4)   // xor16
        return __builtin_bit_cast(float, __builtin_amdgcn_ds_swizzle(
            __builtin_bit_cast(int, v), (16 << 10) | 0x1F));
    else {             // xor32
#if __has_builtin(__builtin_amdgcn_permlane32_swap)
        typedef unsigned uint2v __attribute__((ext_vector_type(2)));
        const unsigned u = __builtin_bit_cast(unsigned, v);
        const uint2v r = __builtin_amdgcn_permlane32_swap(u, u, false, false);
        // r[0]: hi lanes hold lo-partner; r[1]: lo lanes hold hi-partner
        return __builtin_bit_cast(float, (threadIdx.x & 32) ? r[0] : r[1]);
#else
        return __shfl_xor(v, 32);
#endif
    }
}

// 6-stage full-wave butterfly sum (all 64 lanes end with the total).
__device__ __forceinline__ float wred(float v) {
    v += lxor(v, 0);
    v += lxor(v, 1);
    v += lxor(v, 2);
    v += lxor(v, 3);
    v += lxor(v, 4);
    v += lxor(v, 5);
    return v;
}

// CNOT-ring + bit-reversal permutation (R5/R7-verified), GF(2)-linear.
__device__ __forceinline__ int cnotrev(int k) {
    int m = (int)(__brev((unsigned)k) >> 22);
    #pragma unroll
    for (int q = 9; q >= 0; --q) {
        const int pc = (q == 9) ? 0 : 9 - q;
        const int pt = (q == 9) ? 9 : 8 - q;
        m ^= ((m >> pc) & 1) << pt;
    }
    return m;
}

__global__ __launch_bounds__(256) void fused_kernel(const float* __restrict__ w,
                                                    const float* __restrict__ x,
                                                    float* __restrict__ out)
{
    __shared__ float uu[10][8];                    // combined Mz*My*Mx per wire
    __shared__ float ryc[10], rys[10];             // layer-3 RY coefficients
    __shared__ __align__(16) float scr[4][2048];   // per-wave fp32 scratch (8KB)
    const int tid = threadIdx.x;
    const int wv = tid >> 6, l = tid & 63;
    const int row = blockIdx.x * 4 + wv;
    float* bw = scr[wv];

    // ---- per-block setup: combined single-qubit unitaries (uniform) ----
    if (tid < 10) {
        float t0 = w[tid*4 + 0] * 0.5f, t1 = w[tid*4 + 1] * 0.5f;
        float t2 = w[tid*4 + 2] * 0.5f, t3 = w[tid*4 + 3] * 0.5f;
        float s0, c0, s1, c1, s2, c2, s3, c3;
        __sincosf(t0, &s0, &c0);
        __sincosf(t1, &s1, &c1);
        __sincosf(t2, &s2, &c2);
        __sincosf(t3, &s3, &c3);
        // M = Mz*My*Mx (RX applied first) -- R7-verified.
        uu[tid][0] =  c2*c1*c0 + s2*s1*s0;     // u00r
        uu[tid][1] =  c2*s1*s0 - s2*c1*c0;     // u00i
        uu[tid][2] = -(c2*s1*c0 + s2*c1*s0);   // u01r
        uu[tid][3] =  s2*s1*c0 - c2*c1*s0;     // u01i
        uu[tid][4] =  c2*s1*c0 + s2*c1*s0;     // u10r
        uu[tid][5] =  s2*s1*c0 - c2*c1*s0;     // u10i
        uu[tid][6] =  c2*c1*c0 + s2*s1*s0;     // u11r =  u00r
        uu[tid][7] =  s2*c1*c0 - c2*s1*s0;     // u11i = -u00i
        ryc[tid] = c3;
        rys[tid] = s3;
    }
    __syncthreads();

    // ---- load row, normalize (1/||x|| * 1/32 folded into one scale) ----
    const float* xr = x + (size_t)row * 1024 + l * 16;
    float4 v0 = ((const float4*)xr)[0];
    float4 v1 = ((const float4*)xr)[1];
    float4 v2 = ((const float4*)xr)[2];
    float4 v3 = ((const float4*)xr)[3];
    float ss = v0.x*v0.x + v0.y*v0.y + v0.z*v0.z + v0.w*v0.w
             + v1.x*v1.x + v1.y*v1.y + v1.z*v1.z + v1.w*v1.w
             + v2.x*v2.x + v2.y*v2.y + v2.z*v2.z + v2.w*v2.w
             + v3.x*v3.x + v3.y*v3.y + v3.z*v3.z + v3.w*v3.w;
    ss = wred(ss);
    const float scale = 0.03125f / fmaxf(sqrtf(ss), 1e-8f);

    float2 c[16];
    c[0]  = make_float2(v0.x*scale, 0.f); c[1]  = make_float2(v0.y*scale, 0.f);
    c[2]  = make_float2(v0.z*scale, 0.f); c[3]  = make_float2(v0.w*scale, 0.f);
    c[4]  = make_float2(v1.x*scale, 0.f); c[5]  = make_float2(v1.y*scale, 0.f);
    c[6]  = make_float2(v1.z*scale, 0.f); c[7]  = make_float2(v1.w*scale, 0.f);
    c[8]  = make_float2(v2.x*scale, 0.f); c[9]  = make_float2(v2.y*scale, 0.f);
    c[10] = make_float2(v2.z*scale, 0.f); c[11] = make_float2(v2.w*scale, 0.f);
    c[12] = make_float2(v3.x*scale, 0.f); c[13] = make_float2(v3.y*scale, 0.f);
    c[14] = make_float2(v3.z*scale, 0.f); c[15] = make_float2(v3.w*scale, 0.f);

    // ---- combined RX/RY/RZ layers: bit p <-> wire 9-p (R7-verified) ----
    {   // p = 0 (wire 9) peeled: input amps are REAL (c[*].y == 0)
        const float* U = uu[9];
        const float u00r = U[0], u00i = U[1], u01r = U[2], u01i = U[3];
        const float u10r = U[4], u10i = U[5], u11r = U[6], u11i = U[7];
        #pragma unroll
        for (int i = 0; i < 16; i += 2) {
            const int j = i | 1;
            const float ar = c[i].x, br = c[j].x;
            c[i].x = u00r*ar + u01r*br;
            c[i].y = u00i*ar + u01i*br;
            c[j].x = u10r*ar + u11r*br;
            c[j].y = u10i*ar + u11i*br;
        }
    }
    #pragma unroll
    for (int p = 1; p < 4; ++p) {
        const float* U = uu[9 - p];
        const float u00r = U[0], u00i = U[1], u01r = U[2], u01i = U[3];
        const float u10r = U[4], u10i = U[5], u11r = U[6], u11i = U[7];
        const int m = 1 << p;
        #pragma unroll
        for (int i = 0; i < 16; ++i) {
            if (i & m) continue;
            const int j = i | m;
            const float ar = c[i].x, ai = c[i].y, br = c[j].x, bi = c[j].y;
            c[i].x = u00r*ar - u00i*ai + u01r*br - u01i*bi;
            c[i].y = u00r*ai + u00i*ar + u01r*bi + u01i*br;
            c[j].x = u10r*ar - u10i*ai + u11r*br - u11i*bi;
            c[j].y = u10r*ai + u10i*ar + u11r*bi + u11i*br;
        }
    }
    #pragma unroll
    for (int e = 0; e < 6; ++e) {
        const float* U = uu[5 - e];
        const int mybit = (l >> e) & 1;
        const float car = mybit ? U[6] : U[0];
        const float cai = mybit ? U[7] : U[1];
        const float cbr = mybit ? U[4] : U[2];
        const float cbi = mybit ? U[5] : U[3];
        #pragma unroll
        for (int i = 0; i < 16; ++i) {
            const float fr = lxor(c[i].x, e);
            const float fi = lxor(c[i].y, e);
            const float ar = c[i].x, ai = c[i].y;
            c[i].x = car*ar - cai*ai + cbr*fr - cbi*fi;
            c[i].y = car*ai + cai*ar + cbr*fi + cbi*fr;
        }
    }

    // ---- CNOT ring + bit-reversal: wave-local fp32 LDS gather (R7) ----
    #pragma unroll
    for (int j = 0; j < 8; ++j) {
        const int su = l*8 + (j ^ (l & 7));
        ((float4*)bw)[su] = make_float4(c[2*j].x, c[2*j].y, c[2*j+1].x, c[2*j+1].y);
    }
    const int mb = cnotrev(l << 4);
    #pragma unroll
    for (int i = 0; i < 16; ++i) {
        const int m = mb ^ cnotrev(i);          // cnotrev(i) constant-folds
        const int lm = m >> 4, um = (m >> 1) & 7, lo = m & 1;
        const int su = lm*8 + (um ^ (lm & 7));
        c[i] = ((const float2*)bw)[su*2 + lo];
    }

    // ---- layer-3 RY on REVERSED bits: bit p <-> wire p (R7-verified) ----
    #pragma unroll
    for (int p = 0; p < 4; ++p) {
        const float cc = ryc[p], sv = rys[p];
        const int m = 1 << p;
        #pragma unroll
        for (int i = 0; i < 16; ++i) {
            if (i & m) continue;
            const int j = i | m;
            const float ar = c[i].x, ai = c[i].y, br = c[j].x, bi = c[j].y;
            c[i].x = cc*ar - sv*br;  c[i].y = cc*ai - sv*bi;
            c[j].x = sv*ar + cc*br;  c[j].y = sv*ai + cc*bi;
        }
    }
    #pragma unroll
    for (int e = 0; e < 6; ++e) {
        const float cc = ryc[4 + e], sv = rys[4 + e];
        const int mybit = (l >> e) & 1;
        const float sel = mybit ? sv : -sv;
        #pragma unroll
        for (int i = 0; i < 16; ++i) {
            const float fr = lxor(c[i].x, e);
            const float fi = lxor(c[i].y, e);
            c[i].x = cc*c[i].x + sel*fr;
            c[i].y = cc*c[i].y + sel*fi;
        }
    }

    // ---- 1024-pt DIT FFT (bit-reversed input, positive twiddles) ----
    // intra-lane stages 1..4: compile-time pi/8-step twiddle tables
    {
        const float TC8[8] = { 1.f,  0.92387953f,  0.70710678f,  0.38268343f,
                               0.f, -0.38268343f, -0.70710678f, -0.92387953f };
        const float TS8[8] = { 0.f,  0.38268343f,  0.70710678f,  0.92387953f,
                               1.f,  0.92387953f,  0.70710678f,  0.38268343f };
        #pragma unroll
        for (int st = 1; st <= 4; ++st) {
            const int hf = 1 << (st - 1);
            #pragma unroll
            for (int i = 0; i < 16; ++i) {
                if (i & hf) continue;
                const int j = i | hf;
                const int tix = (i & (hf - 1)) << (4 - st);
                const float cwv = TC8[tix], swv = TS8[tix];
                const float tr = cwv*c[j].x - swv*c[j].y;
                const float ti = cwv*c[j].y + swv*c[j].x;
                const float ur = c[i].x, ui = c[i].y;
                c[i].x = ur + tr; c[i].y = ui + ti;
                c[j].x = ur - tr; c[j].y = ui - ti;
            }
        }
    }
    // cross-lane stages 5..10 (lane-bit e2, st = 5+e2):
    //   w(i) = w_base * W^i, W^i compile-time; premultiply-exchange butterfly.
    {
        const float CT[6][16] = {
          { 1.f,0.98078528f,0.92387953f,0.83146961f,0.70710678f,0.55557023f,0.38268343f,0.19509032f,
            0.f,-0.19509032f,-0.38268343f,-0.55557023f,-0.70710678f,-0.83146961f,-0.92387953f,-0.98078528f },
          { 1.f,0.99518473f,0.98078528f,0.95694034f,0.92387953f,0.88192126f,0.83146961f,0.77301045f,
            0.70710678f,0.63439328f,0.55557023f,0.47139674f,0.38268343f,0.29028468f,0.19509032f,0.09801714f },
          { 1.f,0.99879546f,0.99518473f,0.98917651f,0.98078528f,0.97003125f,0.95694034f,0.94154407f,
            0.92387953f,0.90398929f,0.88192126f,0.85772861f,0.83146961f,0.80320753f,0.77301045f,0.74095113f },
          { 1.f,0.99969882f,0.99879546f,0.99729046f,0.99518473f,0.99247953f,0.98917651f,0.98527764f,
            0.98078528f,0.97570213f,0.97003125f,0.96377607f,0.95694034f,0.94952818f,0.94154407f,0.93299280f },
          { 1.f,0.99992470f,0.99969882f,0.99932238f,0.99879546f,0.99811811f,0.99729046f,0.99631261f,
            0.99518473f,0.99390697f,0.99247953f,0.99090264f,0.98917651f,0.98730142f,0.98527764f,0.98310549f },
          { 1.f,0.99998118f,0.99992470f,0.99983058f,0.99969882f,0.99952942f,0.99932238f,0.99907773f,
            0.99879546f,0.99847559f,0.99811811f,0.99772307f,0.99729046f,0.99682030f,0.99631261f,0.99576742f } };
        const float ST[6][16] = {
          { 0.f,0.19509032f,0.38268343f,0.55557023f,0.70710678f,0.83146961f,0.92387953f,0.98078528f,
            1.f,0.98078528f,0.92387953f,0.83146961f,0.70710678f,0.55557023f,0.38268343f,0.19509032f },
          { 0.f,0.09801714f,0.19509032f,0.29028468f,0.38268343f,0.47139674f,0.55557023f,0.63439328f,
            0.70710678f,0.77301045f,0.83146961f,0.88192126f,0.92387953f,0.95694034f,0.98078528f,0.99518473f },
          { 0.f,0.04906767f,0.09801714f,0.14673047f,0.19509032f,0.24298018f,0.29028468f,0.33688985f,
            0.38268343f,0.42755509f,0.47139674f,0.51410274f,0.55557023f,0.59569930f,0.63439328f,0.67155895f },
          { 0.f,0.02454123f,0.04906767f,0.07356456f,0.09801714f,0.12241068f,0.14673047f,0.17096189f,
            0.19509032f,0.21910124f,0.24298018f,0.26671276f,0.29028468f,0.31368174f,0.33688985f,0.35989504f },
          { 0.f,0.01227154f,0.02454123f,0.03680722f,0.04906767f,0.06132074f,0.07356456f,0.08579731f,
            0.09801714f,0.11022221f,0.12241068f,0.13458071f,0.14673047f,0.15885814f,0.17096189f,0.18303989f },
          { 0.f,0.00613588f,0.01227154f,0.01840673f,0.02454123f,0.03067480f,0.03680722f,0.04293826f,
            0.04906767f,0.05519524f,0.06132074f,0.06744392f,0.07356456f,0.07968244f,0.08579731f,0.09190896f } };
        #pragma unroll
        for (int e2 = 0; e2 < 6; ++e2) {
            const int st = 5 + e2;
            const float astep = 6.28318530717958647f / (float)(1 << st);
            const int mybit = (l >> e2) & 1;
            const float sel = mybit ? -1.f : 1.f;
            float cb, sb;
            __sincosf(astep * 16.0f * (float)(l & ((1 << e2) - 1)), &sb, &cb);
            #pragma unroll
            for (int i = 0; i < 16; ++i) {
                const float cw = cb*CT[e2][i] - sb*ST[e2][i];   // wb * W^i
                const float sw = sb*CT[e2][i] + cb*ST[e2][i];
                const float pr = cw*c[i].x - sw*c[i].y;         // w * own
                const float pi = cw*c[i].y + sw*c[i].x;
                const float vr = mybit ? pr : c[i].x;           // b-lane sends w*b
                const float vi = mybit ? pi : c[i].y;
                const float fr = lxor(vr, e2);
                const float fi = lxor(vi, e2);
                c[i].x = fmaf(sel, vr, fr);                     // a: a+w*b, b: a-w*b
                c[i].y = fmaf(sel, vi, fi);
            }
        }
    }

    // ---- expectations ----
    float P2s = 0.f;
    #pragma unroll
    for (int i = 0; i < 16; ++i)
        P2s += c[i].x*c[i].x + c[i].y*c[i].y;

    // Walsh transform of P2s across lanes: lane m ends with
    // W[m] = sum_l (-1)^{popcount(l&m)} P2s(l).  Cross-qubit zz(q=5-e) = W[1<<e].
    float wz = P2s;
    #pragma unroll
    for (int e = 0; e < 6; ++e) {
        const float f = lxor(wz, e);
        wz = ((l >> e) & 1) ? (f - wz) : (wz + f);
    }

    float outv = 0.f;   // lane o ends up holding out[row][o]
    const int par = l & 1;

    // intra-lane qubits: k-bit p = 0..3 -> q = 9-p  (pairs counted once: 2x).
    // rr/ii share ONE parity-packed butterfly; zz uses a plain wred.
    #pragma unroll
    for (int p = 0; p < 4; ++p) {
        const int m = 1 << p;
        const int q = 9 - p;
        float rr = 0.f, ii = 0.f, zz = 0.f;
        #pragma unroll
        for (int i = 0; i < 16; ++i) {
            if (i & m) continue;
            const int j = i | m;
            rr += c[i].x*c[j].x + c[i].y*c[j].y;
            ii += c[i].x*c[j].y - c[i].y*c[j].x;
            zz += (c[i].x*c[i].x + c[i].y*c[i].y) - (c[j].x*c[j].x + c[j].y*c[j].y);
        }
        // packed: even lanes accumulate rr, odd lanes accumulate ii
        const float own  = par ? ii : rr;
        const float send = par ? rr : ii;
        float t = own + lxor(send, 0);
        t += lxor(t, 1); t += lxor(t, 2); t += lxor(t, 3);
        t += lxor(t, 4); t += lxor(t, 5);
        const float u2 = lxor(t, 0);          // opposite parity's total
        const float R = par ? u2 : t;
        const float I = par ? t : u2;
        zz = wred(zz);
        outv = (l == q)      ? 2.f*R : outv;
        outv = (l == 10 + q) ? 2.f*I : outv;
        outv = (l == 20 + q) ? zz    : outv;
    }

    // cross-lane qubits: lane-bit e (k-bit 4+e) -> q = 5-e.
    // Both lanes of a pair compute it -> totals already 2x -> no 2* factor.
    // rr/ii parity-packed; zz comes from the WHT via readlane.
    #pragma unroll
    for (int e = 0; e < 6; ++e) {
        const int q = 5 - e;
        const int mybit = (l >> e) & 1;
        const float sgn = mybit ? -1.f : 1.f;
        float rr = 0.f, ii = 0.f;
        #pragma unroll
        for (int i = 0; i < 16; ++i) {
            const float fr = lxor(c[i].x, e);
            const float fi = lxor(c[i].y, e);
            rr += c[i].x*fr + c[i].y*fi;
            ii += c[i].x*fi - c[i].y*fr;
        }
        const float si = sgn * ii;
        const float own  = par ? si : rr;
        const float send = par ? rr : si;
        float t = own + lxor(send, 0);
        t += lxor(t, 1); t += lxor(t, 2); t += lxor(t, 3);
        t += lxor(t, 4); t += lxor(t, 5);
        const float u2 = lxor(t, 0);
        const float R = par ? u2 : t;
        const float I = par ? t : u2;
        const float Z = __builtin_bit_cast(float,
            __builtin_amdgcn_readlane(__builtin_bit_cast(int, wz), 1 << e));
        outv = (l == q)      ? R : outv;   // already 2*Re
        outv = (l == 10 + q) ? I : outv;   // already 2*Im
        outv = (l == 20 + q) ? Z : outv;
    }

    if (l < 30)
        out[(size_t)row * 30 + l] = outv;
}

// ---------------------------------------------------------------------------
extern "C" void kernel_launch(void* const* d_in, const int* in_sizes, int n_in,
                              void* d_out, int out_size, void* d_ws, size_t ws_size,
                              hipStream_t stream) {
    const float* x = (const float*)d_in[0];   // [8192][1024]
    const float* w = (const float*)d_in[1];   // [10][4]
    float* out = (float*)d_out;               // [8192][30]
    (void)d_ws; (void)ws_size;                // workspace not needed

    fused_kernel<<<2048, 256, 0, stream>>>(w, x, out);
}

// Round 16
// 142.564 us; speedup vs baseline: 1.0877x; 1.0877x over previous
//
#include <hip/hip_runtime.h>

// ---------------------------------------------------------------------------
// QuantumQKGenerator, fully fused (R18 = R16 revert): out[b] = expectations
// of S = QFT * U_circuit * normalize(x[b]).  One wave per row, amps in regs.
//
// R17 post-mortem: the 4-change diet bundle REGRESSED (89.5 -> 101us).
// Mechanism: VGPR 84->88 crossed the 6->5 waves/SIMD boundary (occupancy
// 28->20.7%), and parity-packed reductions replaced two INDEPENDENT wred
// chains (which interleave) with one serial pack->reduce->unpack chain --
// less ILP exactly where the kernel is latency-sensitive.  LESSON: at this
// margin, op-count cuts that lengthen dep chains or bump VGPR across an
// 8-granule boundary are net-negative.
//
// This is the verified best state (R16/R14 bench: 89.5us kernel, VALUBusy
// 81%, VGPR 84, 285K conflicts, absmax 4.88e-4):
//  - lxor: DPP quad_perm (xor1/2), ds_swizzle (xor4/8/16), shfl (xor32)
//  - fused Mz*My*Mx gate layers; GF(2)-linear cnotrev gather (fp32 LDS)
//  - FFT: compile-time twiddle tables, premultiply-exchange butterflies
//  - expect: direct lxor partner exchange, independent wred chains
// ---------------------------------------------------------------------------

// cross-lane XOR exchange; e is compile-time after full unroll, so each
// branch folds and the builtins see literal args.
__device__ __forceinline__ float lxor(float v, int e) {
    if (e == 0)        // quad_perm [1,0,3,2]
        return __builtin_bit_cast(float, __builtin_amdgcn_mov_dpp(
            __builtin_bit_cast(int, v), 0xB1, 0xF, 0xF, true));
    else if (e == 1)   // quad_perm [2,3,0,1]
        return __builtin_bit_cast(float, __builtin_amdgcn_mov_dpp(
            __builtin_bit_cast(int, v), 0x4E, 0xF, 0xF, true));
    else if (e == 2)   // ds_swizzle bit-mode xor4
        return __builtin_bit_cast(float, __builtin_amdgcn_ds_swizzle(
            __builtin_bit_cast(int, v), (4 << 10) | 0x1F));
    else if (e == 3)   // xor8
        return __builtin_bit_cast(float, __builtin_amdgcn_ds_swizzle(
            __builtin_bit_cast(int, v), (8 << 10) | 0x1F));
    else if (e == 4)   // xor16
        return __builtin_bit_cast(float, __builtin_amdgcn_ds_swizzle(
            __builtin_bit_cast(int, v), (16 << 10) | 0x1F));
    else               // xor32: crosses the 32-lane swizzle boundary
        return __shfl_xor(v, 32);
}

// 6-stage full-wave butterfly sum (all 64 lanes end with the total).
__device__ __forceinline__ float wred(float v) {
    v += lxor(v, 0);
    v += lxor(v, 1);
    v += lxor(v, 2);
    v += lxor(v, 3);
    v += lxor(v, 4);
    v += lxor(v, 5);
    return v;
}

// CNOT-ring + bit-reversal permutation (R5/R7-verified), GF(2)-linear.
__device__ __forceinline__ int cnotrev(int k) {
    int m = (int)(__brev((unsigned)k) >> 22);
    #pragma unroll
    for (int q = 9; q >= 0; --q) {
        const int pc = (q == 9) ? 0 : 9 - q;
        const int pt = (q == 9) ? 9 : 8 - q;
        m ^= ((m >> pc) & 1) << pt;
    }
    return m;
}

__global__ __launch_bounds__(256) void fused_kernel(const float* __restrict__ w,
                                                    const float* __restrict__ x,
                                                    float* __restrict__ out)
{
    __shared__ float uu[10][8];                    // combined Mz*My*Mx per wire
    __shared__ float ryc[10], rys[10];             // layer-3 RY coefficients
    __shared__ __align__(16) float scr[4][2048];   // per-wave fp32 scratch (8KB)
    const int tid = threadIdx.x;
    const int wv = tid >> 6, l = tid & 63;
    const int row = blockIdx.x * 4 + wv;
    float* bw = scr[wv];

    // ---- per-block setup: combined single-qubit unitaries (uniform) ----
    if (tid < 10) {
        float t0 = w[tid*4 + 0] * 0.5f, t1 = w[tid*4 + 1] * 0.5f;
        float t2 = w[tid*4 + 2] * 0.5f, t3 = w[tid*4 + 3] * 0.5f;
        float s0, c0, s1, c1, s2, c2, s3, c3;
        __sincosf(t0, &s0, &c0);
        __sincosf(t1, &s1, &c1);
        __sincosf(t2, &s2, &c2);
        __sincosf(t3, &s3, &c3);
        // M = Mz*My*Mx (RX applied first) -- R7-verified.
        uu[tid][0] =  c2*c1*c0 + s2*s1*s0;     // u00r
        uu[tid][1] =  c2*s1*s0 - s2*c1*c0;     // u00i
        uu[tid][2] = -(c2*s1*c0 + s2*c1*s0);   // u01r
        uu[tid][3] =  s2*s1*c0 - c2*c1*s0;     // u01i
        uu[tid][4] =  c2*s1*c0 + s2*c1*s0;     // u10r
        uu[tid][5] =  s2*s1*c0 - c2*c1*s0;     // u10i
        uu[tid][6] =  c2*c1*c0 + s2*s1*s0;     // u11r =  u00r
        uu[tid][7] =  s2*c1*c0 - c2*s1*s0;     // u11i = -u00i
        ryc[tid] = c3;
        rys[tid] = s3;
    }
    __syncthreads();

    // ---- load row, normalize (1/||x|| * 1/32 folded into one scale) ----
    const float* xr = x + (size_t)row * 1024 + l * 16;
    float4 v0 = ((const float4*)xr)[0];
    float4 v1 = ((const float4*)xr)[1];
    float4 v2 = ((const float4*)xr)[2];
    float4 v3 = ((const float4*)xr)[3];
    float ss = v0.x*v0.x + v0.y*v0.y + v0.z*v0.z + v0.w*v0.w
             + v1.x*v1.x + v1.y*v1.y + v1.z*v1.z + v1.w*v1.w
             + v2.x*v2.x + v2.y*v2.y + v2.z*v2.z + v2.w*v2.w
             + v3.x*v3.x + v3.y*v3.y + v3.z*v3.z + v3.w*v3.w;
    ss = wred(ss);
    const float scale = 0.03125f / fmaxf(sqrtf(ss), 1e-8f);

    float2 c[16];
    c[0]  = make_float2(v0.x*scale, 0.f); c[1]  = make_float2(v0.y*scale, 0.f);
    c[2]  = make_float2(v0.z*scale, 0.f); c[3]  = make_float2(v0.w*scale, 0.f);
    c[4]  = make_float2(v1.x*scale, 0.f); c[5]  = make_float2(v1.y*scale, 0.f);
    c[6]  = make_float2(v1.z*scale, 0.f); c[7]  = make_float2(v1.w*scale, 0.f);
    c[8]  = make_float2(v2.x*scale, 0.f); c[9]  = make_float2(v2.y*scale, 0.f);
    c[10] = make_float2(v2.z*scale, 0.f); c[11] = make_float2(v2.w*scale, 0.f);
    c[12] = make_float2(v3.x*scale, 0.f); c[13] = make_float2(v3.y*scale, 0.f);
    c[14] = make_float2(v3.z*scale, 0.f); c[15] = make_float2(v3.w*scale, 0.f);

    // ---- combined RX/RY/RZ layers: bit p <-> wire 9-p (R7-verified) ----
    #pragma unroll
    for (int p = 0; p < 4; ++p) {
        const float* U = uu[9 - p];
        const float u00r = U[0], u00i = U[1], u01r = U[2], u01i = U[3];
        const float u10r = U[4], u10i = U[5], u11r = U[6], u11i = U[7];
        const int m = 1 << p;
        #pragma unroll
        for (int i = 0; i < 16; ++i) {
            if (i & m) continue;
            const int j = i | m;
            const float ar = c[i].x, ai = c[i].y, br = c[j].x, bi = c[j].y;
            c[i].x = u00r*ar - u00i*ai + u01r*br - u01i*bi;
            c[i].y = u00r*ai + u00i*ar + u01r*bi + u01i*br;
            c[j].x = u10r*ar - u10i*ai + u11r*br - u11i*bi;
            c[j].y = u10r*ai + u10i*ar + u11r*bi + u11i*br;
        }
    }
    #pragma unroll
    for (int e = 0; e < 6; ++e) {
        const float* U = uu[5 - e];
        const int mybit = (l >> e) & 1;
        const float car = mybit ? U[6] : U[0];
        const float cai = mybit ? U[7] : U[1];
        const float cbr = mybit ? U[4] : U[2];
        const float cbi = mybit ? U[5] : U[3];
        #pragma unroll
        for (int i = 0; i < 16; ++i) {
            const float fr = lxor(c[i].x, e);
            const float fi = lxor(c[i].y, e);
            const float ar = c[i].x, ai = c[i].y;
            c[i].x = car*ar - cai*ai + cbr*fr - cbi*fi;
            c[i].y = car*ai + cai*ar + cbr*fi + cbi*fr;
        }
    }

    // ---- CNOT ring + bit-reversal: wave-local fp32 LDS gather (R7) ----
    #pragma unroll
    for (int j = 0; j < 8; ++j) {
        const int su = l*8 + (j ^ (l & 7));
        ((float4*)bw)[su] = make_float4(c[2*j].x, c[2*j].y, c[2*j+1].x, c[2*j+1].y);
    }
    const int mb = cnotrev(l << 4);
    #pragma unroll
    for (int i = 0; i < 16; ++i) {
        const int m = mb ^ cnotrev(i);          // cnotrev(i) constant-folds
        const int lm = m >> 4, um = (m >> 1) & 7, lo = m & 1;
        const int su = lm*8 + (um ^ (lm & 7));
        c[i] = ((const float2*)bw)[su*2 + lo];
    }

    // ---- layer-3 RY on REVERSED bits: bit p <-> wire p (R7-verified) ----
    #pragma unroll
    for (int p = 0; p < 4; ++p) {
        const float cc = ryc[p], sv = rys[p];
        const int m = 1 << p;
        #pragma unroll
        for (int i = 0; i < 16; ++i) {
            if (i & m) continue;
            const int j = i | m;
            const float ar = c[i].x, ai = c[i].y, br = c[j].x, bi = c[j].y;
            c[i].x = cc*ar - sv*br;  c[i].y = cc*ai - sv*bi;
            c[j].x = sv*ar + cc*br;  c[j].y = sv*ai + cc*bi;
        }
    }
    #pragma unroll
    for (int e = 0; e < 6; ++e) {
        const float cc = ryc[4 + e], sv = rys[4 + e];
        const int mybit = (l >> e) & 1;
        const float sel = mybit ? sv : -sv;
        #pragma unroll
        for (int i = 0; i < 16; ++i) {
            const float fr = lxor(c[i].x, e);
            const float fi = lxor(c[i].y, e);
            c[i].x = cc*c[i].x + sel*fr;
            c[i].y = cc*c[i].y + sel*fi;
        }
    }

    // ---- 1024-pt DIT FFT (bit-reversed input, positive twiddles) ----
    // intra-lane stages 1..4: compile-time pi/8-step twiddle tables
    {
        const float TC8[8] = { 1.f,  0.92387953f,  0.70710678f,  0.38268343f,
                               0.f, -0.38268343f, -0.70710678f, -0.92387953f };
        const float TS8[8] = { 0.f,  0.38268343f,  0.70710678f,  0.92387953f,
                               1.f,  0.92387953f,  0.70710678f,  0.38268343f };
        #pragma unroll
        for (int st = 1; st <= 4; ++st) {
            const int hf = 1 << (st - 1);
            #pragma unroll
            for (int i = 0; i < 16; ++i) {
                if (i & hf) continue;
                const int j = i | hf;
                const int tix = (i & (hf - 1)) << (4 - st);
                const float cwv = TC8[tix], swv = TS8[tix];
                const float tr = cwv*c[j].x - swv*c[j].y;
                const float ti = cwv*c[j].y + swv*c[j].x;
                const float ur = c[i].x, ui = c[i].y;
                c[i].x = ur + tr; c[i].y = ui + ti;
                c[j].x = ur - tr; c[j].y = ui - ti;
            }
        }
    }
    // cross-lane stages 5..10 (lane-bit e2, st = 5+e2):
    //   w(i) = w_base * W^i, W^i compile-time; premultiply-exchange butterfly.
    {
        const float CT[6][16] = {
          { 1.f,0.98078528f,0.92387953f,0.83146961f,0.70710678f,0.55557023f,0.38268343f,0.19509032f,
            0.f,-0.19509032f,-0.38268343f,-0.55557023f,-0.70710678f,-0.83146961f,-0.92387953f,-0.98078528f },
          { 1.f,0.99518473f,0.98078528f,0.95694034f,0.92387953f,0.88192126f,0.83146961f,0.77301045f,
            0.70710678f,0.63439328f,0.55557023f,0.47139674f,0.38268343f,0.29028468f,0.19509032f,0.09801714f },
          { 1.f,0.99879546f,0.99518473f,0.98917651f,0.98078528f,0.97003125f,0.95694034f,0.94154407f,
            0.92387953f,0.90398929f,0.88192126f,0.85772861f,0.83146961f,0.80320753f,0.77301045f,0.74095113f },
          { 1.f,0.99969882f,0.99879546f,0.99729046f,0.99518473f,0.99247953f,0.98917651f,0.98527764f,
            0.98078528f,0.97570213f,0.97003125f,0.96377607f,0.95694034f,0.94952818f,0.94154407f,0.93299280f },
          { 1.f,0.99992470f,0.99969882f,0.99932238f,0.99879546f,0.99811811f,0.99729046f,0.99631261f,
            0.99518473f,0.99390697f,0.99247953f,0.99090264f,0.98917651f,0.98730142f,0.98527764f,0.98310549f },
          { 1.f,0.99998118f,0.99992470f,0.99983058f,0.99969882f,0.99952942f,0.99932238f,0.99907773f,
            0.99879546f,0.99847559f,0.99811811f,0.99772307f,0.99729046f,0.99682030f,0.99631261f,0.99576742f } };
        const float ST[6][16] = {
          { 0.f,0.19509032f,0.38268343f,0.55557023f,0.70710678f,0.83146961f,0.92387953f,0.98078528f,
            1.f,0.98078528f,0.92387953f,0.83146961f,0.70710678f,0.55557023f,0.38268343f,0.19509032f },
          { 0.f,0.09801714f,0.19509032f,0.29028468f,0.38268343f,0.47139674f,0.55557023f,0.63439328f,
            0.70710678f,0.77301045f,0.83146961f,0.88192126f,0.92387953f,0.95694034f,0.98078528f,0.99518473f },
          { 0.f,0.04906767f,0.09801714f,0.14673047f,0.19509032f,0.24298018f,0.29028468f,0.33688985f,
            0.38268343f,0.42755509f,0.47139674f,0.51410274f,0.55557023f,0.59569930f,0.63439328f,0.67155895f },
          { 0.f,0.02454123f,0.04906767f,0.07356456f,0.09801714f,0.12241068f,0.14673047f,0.17096189f,
            0.19509032f,0.21910124f,0.24298018f,0.26671276f,0.29028468f,0.31368174f,0.33688985f,0.35989504f },
          { 0.f,0.01227154f,0.02454123f,0.03680722f,0.04906767f,0.06132074f,0.07356456f,0.08579731f,
            0.09801714f,0.11022221f,0.12241068f,0.13458071f,0.14673047f,0.15885814f,0.17096189f,0.18303989f },
          { 0.f,0.00613588f,0.01227154f,0.01840673f,0.02454123f,0.03067480f,0.03680722f,0.04293826f,
            0.04906767f,0.05519524f,0.06132074f,0.06744392f,0.07356456f,0.07968244f,0.08579731f,0.09190896f } };
        #pragma unroll
        for (int e2 = 0; e2 < 6; ++e2) {
            const int st = 5 + e2;
            const float astep = 6.28318530717958647f / (float)(1 << st);
            const int mybit = (l >> e2) & 1;
            const float sel = mybit ? -1.f : 1.f;
            float cb, sb;
            __sincosf(astep * 16.0f * (float)(l & ((1 << e2) - 1)), &sb, &cb);
            #pragma unroll
            for (int i = 0; i < 16; ++i) {
                const float cw = cb*CT[e2][i] - sb*ST[e2][i];   // wb * W^i
                const float sw = sb*CT[e2][i] + cb*ST[e2][i];
                const float pr = cw*c[i].x - sw*c[i].y;         // w * own
                const float pi = cw*c[i].y + sw*c[i].x;
                const float vr = mybit ? pr : c[i].x;           // b-lane sends w*b
                const float vi = mybit ? pi : c[i].y;
                const float fr = lxor(vr, e2);
                const float fi = lxor(vi, e2);
                c[i].x = fmaf(sel, vr, fr);                     // a: a+w*b, b: a-w*b
                c[i].y = fmaf(sel, vi, fi);
            }
        }
    }

    // ---- expectations ----
    float P2s = 0.f;
    #pragma unroll
    for (int i = 0; i < 16; ++i)
        P2s += c[i].x*c[i].x + c[i].y*c[i].y;

    float outv = 0.f;   // lane o ends up holding out[row][o]

    // intra-lane qubits: k-bit p = 0..3 -> q = 9-p  (pairs counted once: 2x)
    #pragma unroll
    for (int p = 0; p < 4; ++p) {
        const int m = 1 << p;
        const int q = 9 - p;
        float rr = 0.f, ii = 0.f, zz = 0.f;
        #pragma unroll
        for (int i = 0; i < 16; ++i) {
            if (i & m) continue;
            const int j = i | m;
            rr += c[i].x*c[j].x + c[i].y*c[j].y;
            ii += c[i].x*c[j].y - c[i].y*c[j].x;
            zz += (c[i].x*c[i].x + c[i].y*c[i].y) - (c[j].x*c[j].x + c[j].y*c[j].y);
        }
        rr = wred(rr);
        ii = wred(ii);
        zz = wred(zz);
        outv = (l == q)      ? 2.f*rr : outv;
        outv = (l == 10 + q) ? 2.f*ii : outv;
        outv = (l == 20 + q) ? zz     : outv;
    }

    // cross-lane qubits: lane-bit e (k-bit 4+e) -> q = 5-e.
    // Direct lxor partner exchange (R12-verified math): BOTH lanes of a
    // pair compute it -> wred totals already 2x -> no 2* factor.
    // Re(conj(s0)s1) is swap-symmetric (no select); Im antisymmetric (sgn).
    #pragma unroll
    for (int e = 0; e < 6; ++e) {
        const int q = 5 - e;
        const int mybit = (l >> e) & 1;
        const float sgn = mybit ? -1.f : 1.f;
        float rr = 0.f, ii = 0.f;
        #pragma unroll
        for (int i = 0; i < 16; ++i) {
            const float fr = lxor(c[i].x, e);
            const float fi = lxor(c[i].y, e);
            rr += c[i].x*fr + c[i].y*fi;
            ii += c[i].x*fi - c[i].y*fr;
        }
        const float rr_s = wred(rr);
        const float ii_s = wred(sgn * ii);
        const float zz_s = wred(sgn * P2s);
        outv = (l == q)      ? rr_s : outv;   // already 2*Re
        outv = (l == 10 + q) ? ii_s : outv;   // already 2*Im
        outv = (l == 20 + q) ? zz_s : outv;
    }

    if (l < 30)
        out[(size_t)row * 30 + l] = outv;
}

// ---------------------------------------------------------------------------
extern "C" void kernel_launch(void* const* d_in, const int* in_sizes, int n_in,
                              void* d_out, int out_size, void* d_ws, size_t ws_size,
                              hipStream_t stream) {
    const float* x = (const float*)d_in[0];   // [8192][1024]
    const float* w = (const float*)d_in[1];   // [10][4]
    float* out = (float*)d_out;               // [8192][30]
    (void)d_ws; (void)ws_size;                // workspace not needed

    fused_kernel<<<2048, 256, 0, stream>>>(w, x, out);
}